// Round 13
// baseline (222.462 us; speedup 1.0000x reference)
//
#include <hip/hip_runtime.h>

// AP (average precision @ IoU 0.5/0.75) for B=256, N=4000, G=50.
// Strategy: greedy TP matching -> <=50 TPs per (batch,thr); exact stable
// descending-sort ranks of TPs via 4096-bucket counting sort of the 1.024M
// confidences; AP from TP ranks only.
//
// R1: pos 390us latency loop -> LDS. R2-R4: tp stuck ~145us on 1M global
//     hist atomics -> zero-global-atomic design. R5 crash (LDS>64KB).
// R6: 423us. R7: rank one-wave-per-slot; 260. R8: pos1/pos2 split; 204.
// R9: g-outer neutral. R10: bit-exact divide elimination; 191.
// R11: s1/pos2/u64-key bundle NEUTRAL. ws is ~268MB (fill counters).
// R12: cand->global + greedy split + NBKT=4096 CRASHED: broken shuffle
//     prefix-scan in greedy (pre += shfl_up(cpop) without updating the
//     scanned var) -> poisoned tpIdx -> conf[0xAAAAAAAA] page fault.
// R13: same structure, scan FIXED (x += shfl_up(x, off); pre = x - cpop).

#define B_ 256
#define N_ 4000
#define G_ 50
#define M_ (B_ * N_)        // 1,024,000 proposals total
#define NL_ (B_ * G_)       // 12,800 labels total (= n_labels)
#define NBKT 4096
#define KP 16               // u-tile splits in pos1
#define TILE (NL_ / KP)     // 800

// exact decision thresholds: thr + 2^-25
#define M0_ 0x1.000001p-1   // 0.5  + 2^-25
#define M1_ 0x1.800001p-1   // 0.75 + 2^-25

typedef unsigned long long u64;

__device__ __forceinline__ unsigned bucket_of(float c) {
    unsigned b = (unsigned)(c * 4096.0f);
    return b > (NBKT - 1) ? (NBKT - 1) : b;
}

// ---- Phase 1a: IoU candidate masks (both thr) + LDS-private histogram. ----
// One 1024-thread block per batch; 2 blocks/CU (LDS ~17KB).
__global__ __launch_bounds__(1024) void tp_kernel(
    const float* __restrict__ seg,    // [B,N,2]
    const float* __restrict__ gts,    // [B,G,2]
    const float* __restrict__ conf,   // [B,N]
    u64* __restrict__ gCand,          // [2][B_][G_][64]
    unsigned short* __restrict__ pbh) // [B_][NBKT] per-batch histogram
{
    const int tid  = threadIdx.x;
    const int lane = tid & 63;
    const int wv   = tid >> 6;            // wave id 0..15
    const int b    = blockIdx.x;

    __shared__ float2 gtl[G_];            // 400 B
    __shared__ unsigned hls[NBKT];        // 16 KiB   -> ~17KB total LDS

    #pragma unroll
    for (int k = 0; k < NBKT / 1024; ++k) hls[k * 1024 + tid] = 0u;
    if (tid < G_) gtl[tid] = ((const float2*)gts)[b * G_ + tid];
    __syncthreads();

    // LDS-private histogram of this batch's 4000 scores
    const float* cb = conf + (size_t)b * N_;
    #pragma unroll
    for (int s = 0; s < 4; ++s) {
        int n = s * 1024 + tid;
        if (n < N_) atomicAdd(&hls[bucket_of(cb[n])], 1u);
    }

    // Phase A (g outer, slots inner): props in registers, gt read once per g.
    const float2* sb = (const float2*)(seg + (size_t)b * (N_ * 2));
    float pmin[4], pmax[4], plen[4];
    #pragma unroll
    for (int s = 0; s < 4; ++s) {
        int n = s * 1024 + tid;
        if (n < N_) { float2 v = sb[n]; pmin[s] = v.x; pmax[s] = v.y; }
        else { pmin[s] = 1e9f; pmax[s] = 1e9f; }   // sentinel -> iou 0
        plen[s] = pmax[s] - pmin[s];               // == ref's (amax - amin)
    }
    u64* c0 = gCand + ((size_t)b * G_) * 64;            // thr 0.5 block
    u64* c1 = gCand + ((size_t)(B_ + b) * G_) * 64;     // thr 0.75 block
    for (int g = 0; g < G_; ++g) {
        float2 gt = gtl[g];                        // one LDS broadcast per g
        float glen = gt.y - gt.x;
        u64 m0[4], m1[4];
        #pragma unroll
        for (int s = 0; s < 4; ++s) {
            float inter = fmaxf(fminf(pmax[s], gt.y) - fmaxf(pmin[s], gt.x), 0.0f);
            float uni = plen[s] + glen - inter;    // f32, same op order as ref
            double di = (double)inter;             // exact
            double du = (double)uni;               // exact; uni > 0 always
            m0[s] = __ballot(di > M0_ * du);       // == fl(inter/uni) > 0.5f
            m1[s] = __ballot(di > M1_ * du);       // == fl(inter/uni) > 0.75f
        }
        if (lane == 0) {                           // 8 x 8B stores per g/wave
            #pragma unroll
            for (int s = 0; s < 4; ++s) {
                c0[g * 64 + s * 16 + wv] = m0[s];
                c1[g * 64 + s * 16 + wv] = m1[s];
            }
        }
    }
    __syncthreads();   // hist atomics complete

    // write per-batch histogram row (u16; per-batch bin count <= 4000)
    #pragma unroll
    for (int k = 0; k < NBKT / 1024; ++k) {
        int bin = k * 1024 + tid;
        pbh[(size_t)b * NBKT + bin] = (unsigned short)hls[bin];
    }
}

// ---- Phase 1b: greedy matching. One block per batch; wave0=thr0, wave1=thr1.
__global__ __launch_bounds__(128) void greedy_kernel(
    const u64* __restrict__ gCand,    // [2][B_][G_][64]
    int* __restrict__ tpIdx,          // [2][NL_]
    int* __restrict__ cnt)            // [2][B_]
{
    const int lane = threadIdx.x & 63;
    const int thr_i = threadIdx.x >> 6;
    const int b = blockIdx.x;
    const u64* cm = gCand + ((size_t)(thr_i * B_ + b) * G_) * 64;

    u64 used = 0ull;                     // proposals [lane*64, lane*64+64)
    for (int g = 0; g < G_; ++g) {
        u64 c = cm[g * 64 + lane] & ~used;    // coalesced 512B per wave
        u64 ball = __ballot(c != 0ull);
        if (ball) {
            int fl = __ffsll(ball) - 1;  // lowest lane = lowest proposal range
            if (lane == fl) used |= (c & (0ull - c));   // lowest set bit
        }
    }
    // compacted write of this lane's TPs via CORRECT inclusive shuffle scan
    int cpop = __popcll(used);
    int x = cpop;
    #pragma unroll
    for (int off = 1; off < 64; off <<= 1) {
        int v = __shfl_up(x, off, 64);
        if (lane >= off) x += v;
    }
    int j = x - cpop;                     // exclusive prefix
    u64 u = used;
    while (u) {
        int bit = __ffsll(u) - 1;
        u &= u - 1;
        tpIdx[thr_i * NL_ + b * G_ + j++] = b * N_ + lane * 64 + bit;
    }
    if (lane == 63) cnt[thr_i * B_ + b] = x;   // inclusive total
}

// ---- S1: one block PER BIN; parallel scan of the 256-batch column ---------
__global__ __launch_bounds__(256) void s1_kernel(
    unsigned short* __restrict__ pbh,        // [B_][NBKT] -> becomes prefix
    unsigned* __restrict__ total)            // [NBKT]
{
    __shared__ unsigned sc[256];
    const int bin = blockIdx.x;
    const int b = threadIdx.x;
    unsigned v = pbh[(size_t)b * NBKT + bin];
    sc[b] = v;
    __syncthreads();
    for (int off = 1; off < 256; off <<= 1) {   // inclusive Hillis-Steele
        unsigned add = (b >= off) ? sc[b - off] : 0u;
        __syncthreads();
        sc[b] += add;
        __syncthreads();
    }
    pbh[(size_t)b * NBKT + bin] = (unsigned short)(sc[b] - v);   // exclusive
    if (b == 255) total[bin] = sc[255];
}

// ---- S2: exclusive scan of 4096 bin totals, single block ------------------
__global__ __launch_bounds__(1024) void s2_kernel(
    const unsigned* __restrict__ total, unsigned* __restrict__ binStart)
{
    __shared__ unsigned part[1024];
    int t = threadIdx.x;
    unsigned loc[4];
    unsigned s = 0;
    uint4 v4 = ((const uint4*)total)[t];
    loc[0] = s; s += v4.x;
    loc[1] = s; s += v4.y;
    loc[2] = s; s += v4.z;
    loc[3] = s; s += v4.w;
    part[t] = s;
    __syncthreads();
    for (int off = 1; off < 1024; off <<= 1) {   // inclusive Hillis-Steele
        unsigned add = (t >= off) ? part[t - off] : 0u;
        __syncthreads();
        part[t] += add;
        __syncthreads();
    }
    unsigned base = (t == 0) ? 0u : part[t - 1];
    ((uint4*)binStart)[t] = make_uint4(base + loc[0], base + loc[1],
                                       base + loc[2], base + loc[3]);
}

// ---- Scatter: deterministic positions, zero global atomics ----------------
// key = bits(conf)<<32 | ~idx : u64 ordering == (conf desc, idx asc) exactly.
__global__ __launch_bounds__(1024) void scatter_kernel(
    const float* __restrict__ conf,
    const unsigned short* __restrict__ pbh,  // now the exclusive prefix
    const unsigned* __restrict__ binStart,
    u64* __restrict__ sKey)
{
    __shared__ unsigned baseB[NBKT];   // 16 KiB
    __shared__ unsigned lofs[NBKT];    // 16 KiB
    const int tid = threadIdx.x;
    const int b = blockIdx.x;
    #pragma unroll
    for (int k = 0; k < NBKT / 1024; ++k) {
        int bin = k * 1024 + tid;
        baseB[bin] = binStart[bin] + pbh[(size_t)b * NBKT + bin];
        lofs[bin] = 0u;
    }
    __syncthreads();
    const float* cb = conf + (size_t)b * N_;
    #pragma unroll
    for (int s = 0; s < 4; ++s) {
        int n = s * 1024 + tid;
        if (n < N_) {
            float c = cb[n];
            unsigned bin = bucket_of(c);
            unsigned lo = atomicAdd(&lofs[bin], 1u);   // LDS atomic
            unsigned idx = (unsigned)(b * N_ + n);
            sKey[baseB[bin] + lo] = ((u64)__float_as_uint(c) << 32) | (u64)(0xFFFFFFFFu - idx);
        }
    }
}

// ---- Rank: one WAVE per TP slot; lanes stride the ~250-elem bucket --------
__global__ __launch_bounds__(256) void rank_kernel(
    const float* __restrict__ conf,
    const int* __restrict__ tpIdx,
    const int* __restrict__ cnt,
    const unsigned* __restrict__ total,
    const unsigned* __restrict__ binStart,
    const u64* __restrict__ sKey,
    int* __restrict__ tpRank)
{
    const int lane = threadIdx.x & 63;
    const int w = (blockIdx.x << 2) | (threadIdx.x >> 6);   // global wave id
    if (w >= 2 * NL_) return;
    const int thr_i = w / NL_;
    const int t = w - thr_i * NL_;
    const int batch = t / G_;
    const int j = t - batch * G_;

    if (j < cnt[thr_i * B_ + batch]) {
        int e = tpIdx[thr_i * NL_ + t];
        float c = conf[e];
        u64 keyE = ((u64)__float_as_uint(c) << 32) | (u64)(0xFFFFFFFFu - (unsigned)e);
        unsigned bin = bucket_of(c);
        unsigned lo = binStart[bin], n = total[bin];
        int r = M_ - (int)lo - (int)n;   // strictly-better buckets
        for (unsigned base = 0; base < n; base += 64) {
            unsigned k = base + lane;
            bool pred = (k < n) && (sKey[lo + k] > keyE);
            r += (int)__popcll(__ballot(pred));   // wave-uniform partial sum
        }
        if (lane == 0) tpRank[thr_i * NL_ + t] = r;
    } else {
        if (lane == 0) tpRank[thr_i * NL_ + t] = M_ + t;   // distinct sentinel
    }
}

// ---- Pos1: partial counts, 4 t's per lane, K=16 u-tiles -------------------
__global__ __launch_bounds__(256) void pos1_kernel(
    const int* __restrict__ tpRank,
    int* __restrict__ pcount)          // [2][KP][NL_]
{
    __shared__ alignas(16) int tile[TILE];
    const int k = blockIdx.y, thr_i = blockIdx.z;
    const int* base = tpRank + thr_i * NL_;
    for (int i = threadIdx.x; i < TILE; i += 256)
        tile[i] = base[k * TILE + i];
    __syncthreads();

    const int t0 = blockIdx.x * 1024 + threadIdx.x;
    int r[4], c[4] = {0, 0, 0, 0};
    #pragma unroll
    for (int j = 0; j < 4; ++j) {
        int t = t0 + j * 256;
        r[j] = (t < NL_) ? base[t] : -1;   // ranks >= 0, so c stays 0
    }
    const int4* l4 = (const int4*)tile;
    #pragma unroll 4
    for (int i = 0; i < TILE / 4; ++i) {   // wave-uniform -> LDS broadcast
        int4 v = l4[i];
        #pragma unroll
        for (int j = 0; j < 4; ++j)
            c[j] += (v.x < r[j]) + (v.y < r[j]) + (v.z < r[j]) + (v.w < r[j]);
    }
    #pragma unroll
    for (int j = 0; j < 4; ++j) {
        int t = t0 + j * 256;
        if (t < NL_) pcount[(thr_i * KP + k) * NL_ + t] = c[j];
    }
}

// ---- AP (fused pos2): sum partials -> LDS scatter -> AP. One block/thr. ---
__global__ __launch_bounds__(1024) void ap_kernel(
    const int* __restrict__ tpRank,
    const int* __restrict__ pcount,
    float* __restrict__ out)
{
    const int C = 13;   // 1024*13 = 13312 >= NL_
    __shared__ int sr[NL_];            // 51.2 KiB
    __shared__ float cmax[1024];       // 4 KiB
    __shared__ double red[1024];       // 8 KiB  -> 63.5 KiB total
    int thr_i = blockIdx.x;
    int t = threadIdx.x;

    // pos2 inlined: p = sum of 16 partials; scatter rank into sorted LDS slot
    #pragma unroll
    for (int j = 0; j < C; ++j) {
        int tt = t + j * 1024;         // coalesced
        if (tt < NL_) {
            int p = 0;
            #pragma unroll
            for (int k = 0; k < KP; ++k)
                p += pcount[(thr_i * KP + k) * NL_ + tt];
            sr[p] = tpRank[thr_i * NL_ + tt];   // bijection: every slot written
        }
    }
    __syncthreads();

    float pr[C]; int rk[C];
    #pragma unroll
    for (int k = 0; k < C; ++k) {
        int i = t * C + k;
        rk[k] = (i < NL_) ? sr[i] : 0x7FFFFFFF;
        pr[k] = (rk[k] < M_) ? (float)(i + 1) / (float)(rk[k] + 1) : -1.0f;
    }
    float suf[C];
    float run = -1.0f;
    #pragma unroll
    for (int k = C - 1; k >= 0; --k) { run = fmaxf(run, pr[k]); suf[k] = run; }

    cmax[t] = run;
    __syncthreads();
    for (int off = 1; off < 1024; off <<= 1) {   // inclusive suffix-max scan
        float v = cmax[t];
        float o = (t + off < 1024) ? cmax[t + off] : -1.0f;
        __syncthreads();
        cmax[t] = fmaxf(v, o);
        __syncthreads();
    }
    float follow = (t + 1 < 1024) ? cmax[t + 1] : -1.0f;

    double acc = 0.0;
    #pragma unroll
    for (int k = 0; k < C; ++k) {
        int i = t * C + k;
        if (rk[k] >= 1 && rk[k] < M_) {   // global rank 0 excluded by ref curve
            float smax = fmaxf(suf[k], follow);
            float rhi = (float)(i + 1) / 12800.0f;
            float rlo = (float)i / 12800.0f;
            acc += (double)((rhi - rlo) * smax);
        }
    }
    red[t] = acc;
    __syncthreads();
    for (int off = 512; off >= 1; off >>= 1) {
        if (t < off) red[t] += red[t + off];
        __syncthreads();
    }
    if (t == 0) out[thr_i] = (float)red[0];
}

extern "C" void kernel_launch(void* const* d_in, const int* in_sizes, int n_in,
                              void* d_out, int out_size, void* d_ws, size_t ws_size,
                              hipStream_t stream) {
    const float* scores = (const float*)d_in[0];   // [B,N]
    const float* seg    = (const float*)d_in[1];   // [B,N,2]
    const float* gts    = (const float*)d_in[2];   // [B,G,2]
    float* out = (float*)d_out;

    char* p = (char*)d_ws;
    int*            cnt        = (int*)p;             p += 4096;                     // 2KB used
    int*            tpIdx      = (int*)p;             p += 2 * NL_ * 4;              // 100 KB
    int*            tpRank     = (int*)p;             p += 2 * NL_ * 4;              // 100 KB
    unsigned*       total      = (unsigned*)p;        p += NBKT * 4;                 // 16 KB
    unsigned*       binStart   = (unsigned*)p;        p += NBKT * 4;                 // 16 KB
    unsigned short* pbh        = (unsigned short*)p;  p += (size_t)B_ * NBKT * 2;    // 2 MB
    u64*            gCand      = (u64*)p;             p += (size_t)2 * B_ * G_ * 64 * 8; // 12.8 MB
    u64*            sKey       = (u64*)p;             p += (size_t)M_ * 8;           // 8 MB
    int*            pcount     = (int*)sKey;    // aliases sKey (dead after rank)
    (void)ws_size; (void)in_sizes; (void)n_in; (void)out_size;     // total ~23 MB (ws ~268MB)

    // No memset: every workspace word read downstream is written upstream.
    tp_kernel<<<B_, 1024, 0, stream>>>(seg, gts, scores, gCand, pbh);
    greedy_kernel<<<B_, 128, 0, stream>>>(gCand, tpIdx, cnt);
    s1_kernel<<<NBKT, 256, 0, stream>>>(pbh, total);
    s2_kernel<<<1, 1024, 0, stream>>>(total, binStart);
    scatter_kernel<<<B_, 1024, 0, stream>>>(scores, pbh, binStart, sKey);
    rank_kernel<<<(2 * NL_ + 3) / 4, 256, 0, stream>>>(scores, tpIdx, cnt,
                                                       total, binStart, sKey, tpRank);
    pos1_kernel<<<dim3(13, KP, 2), 256, 0, stream>>>(tpRank, pcount);
    ap_kernel<<<2, 1024, 0, stream>>>(tpRank, pcount, out);
}

// Round 14
// 187.572 us; speedup vs baseline: 1.1860x; 1.1860x over previous
//
#include <hip/hip_runtime.h>

// AP (average precision @ IoU 0.5/0.75) for B=256, N=4000, G=50.
// Strategy: greedy TP matching -> <=50 TPs per (batch,thr); exact stable
// descending-sort ranks of TPs via 2048-bucket counting sort of the 1.024M
// confidences; AP from TP ranks only.
//
// R1: pos 390us latency loop -> LDS. R2-R4: tp stuck ~145us on 1M global
//     hist atomics -> zero-global-atomic design. R5 crash (LDS>64KB).
// R6: 423us. R7: rank one-wave-per-slot; 260. R8: pos1/pos2 split; 204.
// R9: g-outer neutral. R10: bit-exact divide elimination; 191.
// R11: s1/pos2/u64-key bundle neutral; 192.
// R12/R13: cand->global eviction REGRESSED (222us): grid==256 blocks on
//     256 CUs -> always 1 block/CU, LDS size was never the occupancy
//     limiter; eviction just added 12.8MB of 8B stores (VALUBusy 59->34,
//     vmcnt-stalled). LESSON: at grid==CU-count, LDS < 64KB is FREE.
// R14: revert to R11 structure; NBKT 1024->2048 (tp LDS 59.8KB still free;
//     rank bucket scans halve: 205->102MB).

#define B_ 256
#define N_ 4000
#define G_ 50
#define M_ (B_ * N_)        // 1,024,000 proposals total
#define NL_ (B_ * G_)       // 12,800 labels total (= n_labels)
#define NBKT 2048
#define KP 16               // u-tile splits in pos1
#define TILE (NL_ / KP)     // 800

// exact decision thresholds: thr + 2^-25
#define M0_ 0x1.000001p-1   // 0.5  + 2^-25
#define M1_ 0x1.800001p-1   // 0.75 + 2^-25

typedef unsigned long long u64;

__device__ __forceinline__ unsigned bucket_of(float c) {
    unsigned b = (unsigned)(c * 2048.0f);
    return b > (NBKT - 1) ? (NBKT - 1) : b;
}

// ---- Phase 1: IoU cand masks + greedy (both thr) + LDS histogram. ---------
// One 1024-thread block per batch; grid==256 -> 1 block/CU, LDS is free.
__global__ __launch_bounds__(1024) void tp_kernel(
    const float* __restrict__ seg,    // [B,N,2]
    const float* __restrict__ gts,    // [B,G,2]
    const float* __restrict__ conf,   // [B,N]
    int* __restrict__ tpIdx,          // [2][NL_], slots [b*50, b*50+cnt)
    int* __restrict__ cnt,            // [2][B_]
    unsigned short* __restrict__ pbh) // [B_][NBKT] per-batch histogram
{
    const int tid  = threadIdx.x;
    const int lane = tid & 63;
    const int wv   = tid >> 6;            // wave id 0..15
    const int b    = blockIdx.x;

    __shared__ float2 gtl[G_];            // 400 B
    __shared__ u64 cand[2][G_][64];       // 51.2 KiB
    __shared__ unsigned hls[NBKT];        // 8 KiB
    __shared__ int lcnt[2];               // total 59.8 KiB < 64 KiB

    #pragma unroll
    for (int k = 0; k < NBKT / 1024; ++k) hls[k * 1024 + tid] = 0u;
    if (tid < G_) gtl[tid] = ((const float2*)gts)[b * G_ + tid];
    if (tid < 2) lcnt[tid] = 0;
    __syncthreads();

    // LDS-private histogram of this batch's 4000 scores
    const float* cb = conf + (size_t)b * N_;
    #pragma unroll
    for (int s = 0; s < 4; ++s) {
        int n = s * 1024 + tid;
        if (n < N_) atomicAdd(&hls[bucket_of(cb[n])], 1u);
    }

    // Phase A (g outer, slots inner): props in registers, gt read once per g.
    const float2* sb = (const float2*)(seg + (size_t)b * (N_ * 2));
    float pmin[4], pmax[4], plen[4];
    #pragma unroll
    for (int s = 0; s < 4; ++s) {
        int n = s * 1024 + tid;
        if (n < N_) { float2 v = sb[n]; pmin[s] = v.x; pmax[s] = v.y; }
        else { pmin[s] = 1e9f; pmax[s] = 1e9f; }   // sentinel -> iou 0
        plen[s] = pmax[s] - pmin[s];               // == ref's (amax - amin)
    }
    for (int g = 0; g < G_; ++g) {
        float2 gt = gtl[g];                        // one LDS broadcast per g
        float glen = gt.y - gt.x;
        u64 m0[4], m1[4];
        #pragma unroll
        for (int s = 0; s < 4; ++s) {
            float inter = fmaxf(fminf(pmax[s], gt.y) - fmaxf(pmin[s], gt.x), 0.0f);
            float uni = plen[s] + glen - inter;    // f32, same op order as ref
            double di = (double)inter;             // exact
            double du = (double)uni;               // exact; uni > 0 always
            m0[s] = __ballot(di > M0_ * du);       // == fl(inter/uni) > 0.5f
            m1[s] = __ballot(di > M1_ * du);       // == fl(inter/uni) > 0.75f
        }
        if (lane == 0) {                           // one branch, 8 LDS stores
            #pragma unroll
            for (int s = 0; s < 4; ++s) {
                cand[0][g][s * 16 + wv] = m0[s];
                cand[1][g][s * 16 + wv] = m1[s];
            }
        }
    }
    __syncthreads();   // cand complete + hist complete

    // write per-batch histogram row (u16; per-batch bin count <= 4000)
    #pragma unroll
    for (int k = 0; k < NBKT / 1024; ++k) {
        int bin = k * 1024 + tid;
        pbh[(size_t)b * NBKT + bin] = (unsigned short)hls[bin];
    }

    // Phase B: wave 0 -> thr 0.5, wave 1 -> thr 0.75. Greedy via ballot+ffs.
    if (wv < 2) {
        const int thr_i = wv;
        u64 used = 0ull;                     // proposals [lane*64, lane*64+64)
        for (int g = 0; g < G_; ++g) {
            u64 c = cand[thr_i][g][lane] & ~used;
            u64 ball = __ballot(c != 0ull);
            if (ball) {
                int fl = __ffsll(ball) - 1;  // lowest lane = lowest proposal range
                if (lane == fl) used |= (c & (0ull - c));   // lowest set bit
            }
        }
        int cpop = __popcll(used);
        if (cpop) {
            int j = atomicAdd(&lcnt[thr_i], cpop);   // LDS atomic, block-local
            u64 u = used;
            while (u) {
                int bit = __ffsll(u) - 1;
                u &= u - 1;
                tpIdx[thr_i * NL_ + b * G_ + j++] = b * N_ + lane * 64 + bit;
            }
        }
    }
    __syncthreads();
    if (tid < 2) cnt[tid * B_ + b] = lcnt[tid];
}

// ---- S1: one block PER BIN; parallel scan of the 256-batch column ---------
__global__ __launch_bounds__(256) void s1_kernel(
    unsigned short* __restrict__ pbh,        // [B_][NBKT] -> becomes prefix
    unsigned* __restrict__ total)            // [NBKT]
{
    __shared__ unsigned sc[256];
    const int bin = blockIdx.x;
    const int b = threadIdx.x;
    unsigned v = pbh[(size_t)b * NBKT + bin];
    sc[b] = v;
    __syncthreads();
    for (int off = 1; off < 256; off <<= 1) {   // inclusive Hillis-Steele
        unsigned add = (b >= off) ? sc[b - off] : 0u;
        __syncthreads();
        sc[b] += add;
        __syncthreads();
    }
    pbh[(size_t)b * NBKT + bin] = (unsigned short)(sc[b] - v);   // exclusive
    if (b == 255) total[bin] = sc[255];
}

// ---- S2: exclusive scan of 2048 bin totals, single block ------------------
__global__ __launch_bounds__(1024) void s2_kernel(
    const unsigned* __restrict__ total, unsigned* __restrict__ binStart)
{
    __shared__ unsigned part[1024];
    int t = threadIdx.x;
    uint2 v2 = ((const uint2*)total)[t];
    unsigned s = v2.x + v2.y;
    part[t] = s;
    __syncthreads();
    for (int off = 1; off < 1024; off <<= 1) {   // inclusive Hillis-Steele
        unsigned add = (t >= off) ? part[t - off] : 0u;
        __syncthreads();
        part[t] += add;
        __syncthreads();
    }
    unsigned base = (t == 0) ? 0u : part[t - 1];
    ((uint2*)binStart)[t] = make_uint2(base, base + v2.x);
}

// ---- Scatter: deterministic positions, zero global atomics ----------------
// key = bits(conf)<<32 | ~idx : u64 ordering == (conf desc, idx asc) exactly.
__global__ __launch_bounds__(1024) void scatter_kernel(
    const float* __restrict__ conf,
    const unsigned short* __restrict__ pbh,  // now the exclusive prefix
    const unsigned* __restrict__ binStart,
    u64* __restrict__ sKey)
{
    __shared__ unsigned baseB[NBKT];   // 8 KiB
    __shared__ unsigned lofs[NBKT];    // 8 KiB
    const int tid = threadIdx.x;
    const int b = blockIdx.x;
    #pragma unroll
    for (int k = 0; k < NBKT / 1024; ++k) {
        int bin = k * 1024 + tid;
        baseB[bin] = binStart[bin] + pbh[(size_t)b * NBKT + bin];
        lofs[bin] = 0u;
    }
    __syncthreads();
    const float* cb = conf + (size_t)b * N_;
    #pragma unroll
    for (int s = 0; s < 4; ++s) {
        int n = s * 1024 + tid;
        if (n < N_) {
            float c = cb[n];
            unsigned bin = bucket_of(c);
            unsigned lo = atomicAdd(&lofs[bin], 1u);   // LDS atomic
            unsigned idx = (unsigned)(b * N_ + n);
            sKey[baseB[bin] + lo] = ((u64)__float_as_uint(c) << 32) | (u64)(0xFFFFFFFFu - idx);
        }
    }
}

// ---- Rank: one WAVE per TP slot; lanes stride the ~500-elem bucket --------
__global__ __launch_bounds__(256) void rank_kernel(
    const float* __restrict__ conf,
    const int* __restrict__ tpIdx,
    const int* __restrict__ cnt,
    const unsigned* __restrict__ total,
    const unsigned* __restrict__ binStart,
    const u64* __restrict__ sKey,
    int* __restrict__ tpRank)
{
    const int lane = threadIdx.x & 63;
    const int w = (blockIdx.x << 2) | (threadIdx.x >> 6);   // global wave id
    if (w >= 2 * NL_) return;
    const int thr_i = w / NL_;
    const int t = w - thr_i * NL_;
    const int batch = t / G_;
    const int j = t - batch * G_;

    if (j < cnt[thr_i * B_ + batch]) {
        int e = tpIdx[thr_i * NL_ + t];
        float c = conf[e];
        u64 keyE = ((u64)__float_as_uint(c) << 32) | (u64)(0xFFFFFFFFu - (unsigned)e);
        unsigned bin = bucket_of(c);
        unsigned lo = binStart[bin], n = total[bin];
        int r = M_ - (int)lo - (int)n;   // strictly-better buckets
        for (unsigned base = 0; base < n; base += 64) {
            unsigned k = base + lane;
            bool pred = (k < n) && (sKey[lo + k] > keyE);
            r += (int)__popcll(__ballot(pred));   // wave-uniform partial sum
        }
        if (lane == 0) tpRank[thr_i * NL_ + t] = r;
    } else {
        if (lane == 0) tpRank[thr_i * NL_ + t] = M_ + t;   // distinct sentinel
    }
}

// ---- Pos1: partial counts, 4 t's per lane, K=16 u-tiles -------------------
__global__ __launch_bounds__(256) void pos1_kernel(
    const int* __restrict__ tpRank,
    int* __restrict__ pcount)          // [2][KP][NL_]
{
    __shared__ alignas(16) int tile[TILE];
    const int k = blockIdx.y, thr_i = blockIdx.z;
    const int* base = tpRank + thr_i * NL_;
    for (int i = threadIdx.x; i < TILE; i += 256)
        tile[i] = base[k * TILE + i];
    __syncthreads();

    const int t0 = blockIdx.x * 1024 + threadIdx.x;
    int r[4], c[4] = {0, 0, 0, 0};
    #pragma unroll
    for (int j = 0; j < 4; ++j) {
        int t = t0 + j * 256;
        r[j] = (t < NL_) ? base[t] : -1;   // ranks >= 0, so c stays 0
    }
    const int4* l4 = (const int4*)tile;
    #pragma unroll 4
    for (int i = 0; i < TILE / 4; ++i) {   // wave-uniform -> LDS broadcast
        int4 v = l4[i];
        #pragma unroll
        for (int j = 0; j < 4; ++j)
            c[j] += (v.x < r[j]) + (v.y < r[j]) + (v.z < r[j]) + (v.w < r[j]);
    }
    #pragma unroll
    for (int j = 0; j < 4; ++j) {
        int t = t0 + j * 256;
        if (t < NL_) pcount[(thr_i * KP + k) * NL_ + t] = c[j];
    }
}

// ---- AP (fused pos2): sum partials -> LDS scatter -> AP. One block/thr. ---
__global__ __launch_bounds__(1024) void ap_kernel(
    const int* __restrict__ tpRank,
    const int* __restrict__ pcount,
    float* __restrict__ out)
{
    const int C = 13;   // 1024*13 = 13312 >= NL_
    __shared__ int sr[NL_];            // 51.2 KiB
    __shared__ float cmax[1024];       // 4 KiB
    __shared__ double red[1024];       // 8 KiB  -> 63.5 KiB total
    int thr_i = blockIdx.x;
    int t = threadIdx.x;

    // pos2 inlined: p = sum of 16 partials; scatter rank into sorted LDS slot
    #pragma unroll
    for (int j = 0; j < C; ++j) {
        int tt = t + j * 1024;         // coalesced
        if (tt < NL_) {
            int p = 0;
            #pragma unroll
            for (int k = 0; k < KP; ++k)
                p += pcount[(thr_i * KP + k) * NL_ + tt];
            sr[p] = tpRank[thr_i * NL_ + tt];   // bijection: every slot written
        }
    }
    __syncthreads();

    float pr[C]; int rk[C];
    #pragma unroll
    for (int k = 0; k < C; ++k) {
        int i = t * C + k;
        rk[k] = (i < NL_) ? sr[i] : 0x7FFFFFFF;
        pr[k] = (rk[k] < M_) ? (float)(i + 1) / (float)(rk[k] + 1) : -1.0f;
    }
    float suf[C];
    float run = -1.0f;
    #pragma unroll
    for (int k = C - 1; k >= 0; --k) { run = fmaxf(run, pr[k]); suf[k] = run; }

    cmax[t] = run;
    __syncthreads();
    for (int off = 1; off < 1024; off <<= 1) {   // inclusive suffix-max scan
        float v = cmax[t];
        float o = (t + off < 1024) ? cmax[t + off] : -1.0f;
        __syncthreads();
        cmax[t] = fmaxf(v, o);
        __syncthreads();
    }
    float follow = (t + 1 < 1024) ? cmax[t + 1] : -1.0f;

    double acc = 0.0;
    #pragma unroll
    for (int k = 0; k < C; ++k) {
        int i = t * C + k;
        if (rk[k] >= 1 && rk[k] < M_) {   // global rank 0 excluded by ref curve
            float smax = fmaxf(suf[k], follow);
            float rhi = (float)(i + 1) / 12800.0f;
            float rlo = (float)i / 12800.0f;
            acc += (double)((rhi - rlo) * smax);
        }
    }
    red[t] = acc;
    __syncthreads();
    for (int off = 512; off >= 1; off >>= 1) {
        if (t < off) red[t] += red[t + off];
        __syncthreads();
    }
    if (t == 0) out[thr_i] = (float)red[0];
}

extern "C" void kernel_launch(void* const* d_in, const int* in_sizes, int n_in,
                              void* d_out, int out_size, void* d_ws, size_t ws_size,
                              hipStream_t stream) {
    const float* scores = (const float*)d_in[0];   // [B,N]
    const float* seg    = (const float*)d_in[1];   // [B,N,2]
    const float* gts    = (const float*)d_in[2];   // [B,G,2]
    float* out = (float*)d_out;

    char* p = (char*)d_ws;
    int*            cnt        = (int*)p;             p += 4096;                  // 2KB used
    int*            tpIdx      = (int*)p;             p += 2 * NL_ * 4;           // 100 KB
    int*            tpRank     = (int*)p;             p += 2 * NL_ * 4;           // 100 KB
    unsigned*       total      = (unsigned*)p;        p += NBKT * 4;              // 8 KB
    unsigned*       binStart   = (unsigned*)p;        p += NBKT * 4;              // 8 KB
    unsigned short* pbh        = (unsigned short*)p;  p += (size_t)B_ * NBKT * 2; // 1 MB
    u64*            sKey       = (u64*)p;             p += (size_t)M_ * 8;        // 8 MB
    int*            pcount     = (int*)sKey;    // aliases sKey (dead after rank)
    (void)ws_size; (void)in_sizes; (void)n_in; (void)out_size;

    // No memset: every workspace word read downstream is written upstream.
    tp_kernel<<<B_, 1024, 0, stream>>>(seg, gts, scores, tpIdx, cnt, pbh);
    s1_kernel<<<NBKT, 256, 0, stream>>>(pbh, total);
    s2_kernel<<<1, 1024, 0, stream>>>(total, binStart);
    scatter_kernel<<<B_, 1024, 0, stream>>>(scores, pbh, binStart, sKey);
    rank_kernel<<<(2 * NL_ + 3) / 4, 256, 0, stream>>>(scores, tpIdx, cnt,
                                                       total, binStart, sKey, tpRank);
    pos1_kernel<<<dim3(13, KP, 2), 256, 0, stream>>>(tpRank, pcount);
    ap_kernel<<<2, 1024, 0, stream>>>(tpRank, pcount, out);
}